// Round 1
// baseline (52440.460 us; speedup 1.0000x reference)
//
#include <hip/hip_runtime.h>
#include <cmath>

#define B_ 128
#define T_ 1024
#define I_ 256
#define H_ 512
#define O_ 128

#define BGROUPS 4                 // batch groups (32 rows each)
#define ROWS (B_/BGROUPS)         // 32
#define CGROUPS 64                // column groups per batch group
#define HC (H_/CGROUPS)           // 8 h-columns per block
#define NBLK (BGROUPS*CGROUPS)    // 256 blocks == 256 CUs, 1 block/CU (LDS-limited)
#define NTHR 256

// padded LDS strides: bank(row) = (12*row) % 32 -> all 8 distinct, conflict-free
#define SI 268
#define SH 524

#define LDS_FLOATS (3*HC*SI + 3*HC*SH + ROWS*SH)   // 6432 + 12576 + 16768 = 35776 floats = 143104 B

__global__ __launch_bounds__(NTHR, 1)
void gru_persistent(const float* __restrict__ x,
                    const float* __restrict__ Wih,
                    const float* __restrict__ Whh,
                    const float* __restrict__ bih,
                    const float* __restrict__ bhh,
                    float* __restrict__ hA,
                    float* __restrict__ hB,
                    unsigned int* __restrict__ cnt)
{
    extern __shared__ float smem[];
    float* wih = smem;                    // [3][HC][SI]
    float* whh = smem + 3*HC*SI;          // [3][HC][SH]
    float* buf = whh + 3*HC*SH;           // [ROWS][SH] staging for x_t / h_t tiles

    const int tid = threadIdx.x;
    const int g   = blockIdx.x >> 6;      // batch group 0..3
    const int rb0 = g * ROWS;
    const int hc0 = (blockIdx.x & 63) * HC;

    const int row = tid >> 3;             // 0..31 local batch row
    const int hl  = tid & 7;              // 0..7 local h col
    const int j   = hc0 + hl;             // global h col

    // ---- one-time weight preload into LDS ----
    for (int e = tid; e < 3*HC*I_; e += NTHR) {      // 6144 elems
        int gate = e >> 11;
        int rem  = e & 2047;
        int hh   = rem >> 8;
        int i    = rem & 255;
        wih[(gate*HC + hh)*SI + i] = Wih[(gate*H_ + hc0 + hh)*I_ + i];
    }
    for (int e = tid; e < 3*HC*H_; e += NTHR) {      // 12288 elems
        int gate = e >> 12;
        int rem  = e & 4095;
        int hh   = rem >> 9;
        int k    = rem & 511;
        whh[(gate*HC + hh)*SH + k] = Whh[(gate*H_ + hc0 + hh)*H_ + k];
    }
    const float bR  = bih[j] + bhh[j];
    const float bZ  = bih[H_ + j] + bhh[H_ + j];
    const float bNx = bih[2*H_ + j];
    const float bNh = bhh[2*H_ + j];
    __syncthreads();

    const float* br  = buf + row*SH;
    const float* wr0 = wih + hl*SI;
    const float* wr1 = wih + (HC + hl)*SI;
    const float* wr2 = wih + (2*HC + hl)*SI;
    const float* vr0 = whh + hl*SH;
    const float* vr1 = whh + (HC + hl)*SH;
    const float* vr2 = whh + (2*HC + hl)*SH;

    unsigned int* mycnt = cnt + g*T_;

#pragma unroll 1
    for (int t = 0; t < T_; ++t) {
        const float* hread  = (t & 1) ? hB : hA;   // t=0 reads hA (zeros)
        float*       hwrite = (t & 1) ? hA : hB;   // t=1023 writes hA

        // ---- stage x_t tile: 32 rows x 256 (tid == i, coalesced) ----
#pragma unroll 4
        for (int jj = 0; jj < ROWS; ++jj) {
            buf[jj*SH + tid] = x[((rb0 + jj)*T_ + t)*I_ + tid];
        }
        __syncthreads();

        float aR = 0.f, aZ = 0.f, aNx = 0.f, aNh = 0.f;
#pragma unroll 4
        for (int i = 0; i < I_; i += 4) {
            const float4 xv = *(const float4*)(br + i);
            const float4 a0 = *(const float4*)(wr0 + i);
            const float4 a1 = *(const float4*)(wr1 + i);
            const float4 a2 = *(const float4*)(wr2 + i);
            aR  += xv.x*a0.x + xv.y*a0.y + xv.z*a0.z + xv.w*a0.w;
            aZ  += xv.x*a1.x + xv.y*a1.y + xv.z*a1.z + xv.w*a1.w;
            aNx += xv.x*a2.x + xv.y*a2.y + xv.z*a2.z + xv.w*a2.w;
        }
        __syncthreads();

        // ---- stage h tile: 32 rows x 512 ----
#pragma unroll 4
        for (int e = tid; e < ROWS*H_; e += NTHR) {
            int r2 = e >> 9;
            int k  = e & 511;
            buf[r2*SH + k] = hread[(rb0 + r2)*H_ + k];
        }
        __syncthreads();

#pragma unroll 4
        for (int k = 0; k < H_; k += 4) {
            const float4 hv = *(const float4*)(br + k);
            const float4 c0 = *(const float4*)(vr0 + k);
            const float4 c1 = *(const float4*)(vr1 + k);
            const float4 c2 = *(const float4*)(vr2 + k);
            aR  += hv.x*c0.x + hv.y*c0.y + hv.z*c0.z + hv.w*c0.w;
            aZ  += hv.x*c1.x + hv.y*c1.y + hv.z*c1.z + hv.w*c1.w;
            aNh += hv.x*c2.x + hv.y*c2.y + hv.z*c2.z + hv.w*c2.w;
        }

        const float hprev = br[j];
        const float rg = 1.f / (1.f + expf(-(aR + bR)));
        const float zg = 1.f / (1.f + expf(-(aZ + bZ)));
        const float ng = tanhf(aNx + bNx + rg * (aNh + bNh));
        const float hnew = (1.f - zg) * ng + zg * hprev;
        hwrite[(rb0 + row)*H_ + j] = hnew;

        // ---- inter-block barrier within batch group (ticket counter per step) ----
        __threadfence();                  // agent-scope: flush this thread's h store
        __syncthreads();
        if (tid == 0) {
            __hip_atomic_fetch_add(mycnt + t, 1u, __ATOMIC_RELAXED, __HIP_MEMORY_SCOPE_AGENT);
            while (__hip_atomic_load(mycnt + t, __ATOMIC_RELAXED, __HIP_MEMORY_SCOPE_AGENT)
                   < (unsigned)CGROUPS) {
                __builtin_amdgcn_s_sleep(2);
            }
            __builtin_amdgcn_fence(__ATOMIC_ACQUIRE, "agent");  // invalidate L1/L2 before reading peers' h
        }
        __syncthreads();
    }
}

__global__ __launch_bounds__(NTHR)
void fc_kernel(const float* __restrict__ h,
               const float* __restrict__ fcW,
               const float* __restrict__ fcb,
               float* __restrict__ out)
{
    const int gid = blockIdx.x * blockDim.x + threadIdx.x;   // 16384
    const int b = gid >> 7;
    const int o = gid & 127;
    const float* hr = h + b*H_;
    const float* wr = fcW + o*H_;
    float acc = 0.f;
#pragma unroll 8
    for (int k = 0; k < H_; k += 4) {
        const float4 hv = *(const float4*)(hr + k);
        const float4 wv = *(const float4*)(wr + k);
        acc += hv.x*wv.x + hv.y*wv.y + hv.z*wv.z + hv.w*wv.w;
    }
    out[gid] = acc + fcb[o];
}

extern "C" void kernel_launch(void* const* d_in, const int* in_sizes, int n_in,
                              void* d_out, int out_size, void* d_ws, size_t ws_size,
                              hipStream_t stream)
{
    const float* x   = (const float*)d_in[0];
    const float* Wih = (const float*)d_in[1];
    const float* Whh = (const float*)d_in[2];
    const float* bih = (const float*)d_in[3];
    const float* bhh = (const float*)d_in[4];
    const float* fcW = (const float*)d_in[5];
    const float* fcb = (const float*)d_in[6];
    float* out = (float*)d_out;

    float* hA = (float*)d_ws;                 // [128][512] fp32
    float* hB = hA + B_*H_;
    unsigned int* cnt = (unsigned int*)(hB + B_*H_);   // [BGROUPS][T_]

    const size_t init_bytes = (size_t)(2*B_*H_)*sizeof(float)
                            + (size_t)BGROUPS*T_*sizeof(unsigned int);
    hipMemsetAsync(d_ws, 0, init_bytes, stream);   // h0 = 0, counters = 0 (every replay)

    hipFuncSetAttribute(reinterpret_cast<const void*>(gru_persistent),
                        hipFuncAttributeMaxDynamicSharedMemorySize,
                        (int)(LDS_FLOATS * sizeof(float)));

    hipLaunchKernelGGL(gru_persistent, dim3(NBLK), dim3(NTHR),
                       LDS_FLOATS * sizeof(float), stream,
                       x, Wih, Whh, bih, bhh, hA, hB, cnt);

    hipLaunchKernelGGL(fc_kernel, dim3((B_*O_)/NTHR), dim3(NTHR), 0, stream,
                       hA, fcW, fcb, out);   // final h is in hA (t=1023 writes hA)
}

// Round 2
// 9858.652 us; speedup vs baseline: 5.3192x; 5.3192x over previous
//
#include <hip/hip_runtime.h>

#define B_ 128
#define T_ 1024
#define I_ 256
#define H_ 512
#define O_ 128

#define BGROUPS 4
#define ROWS 32            // B_/BGROUPS
#define CGROUPS 64
#define HC 8               // H_/CGROUPS
#define NBLK (BGROUPS*CGROUPS)   // 256
#define NTHR 256

#define KTX 8              // I_/32 k-tiles for x
#define KTH 16             // H_/32 k-tiles for h

// LDS byte offsets (fragment-ordered buffers; 1 KiB per (kt,slot) frag slab)
#define OFF_BIH 0                  // 8kt*2nt*1024  = 16384
#define OFF_BHH 16384              // 16kt*2nt*1024 = 32768
#define OFF_AX  49152              // 8kt*2mt*1024  = 16384
#define OFF_AH  65536              // 16kt*2mt*1024 = 32768
#define OFF_CX  98304              // 2hh*32col*36row*4 = 9216
#define OFF_CH  107520             // 9216
#define LDS_BYTES 116736

#define HSLAB (B_*(H_/2))          // u32 elems per h slab (bf16 pairs): 32768
#define FLAGS_OFF (2*HSLAB)        // u32 offset of flags in ws
#define WS_INIT_BYTES ((2*HSLAB + T_*BGROUPS*64)*4)   // 1,310,720 B

typedef __attribute__((ext_vector_type(8))) short short8;
typedef __attribute__((ext_vector_type(4))) float f32x4;

__device__ __forceinline__ unsigned int bf16rne(float f) {
    unsigned int u = __builtin_bit_cast(unsigned int, f);
    u += 0x7fffu + ((u >> 16) & 1u);
    return u >> 16;
}
__device__ __forceinline__ short8 cvt8(const float* p) {
    float4 a = *(const float4*)p;
    float4 b = *(const float4*)(p + 4);
    short8 r;
    r[0]=(short)bf16rne(a.x); r[1]=(short)bf16rne(a.y); r[2]=(short)bf16rne(a.z); r[3]=(short)bf16rne(a.w);
    r[4]=(short)bf16rne(b.x); r[5]=(short)bf16rne(b.y); r[6]=(short)bf16rne(b.z); r[7]=(short)bf16rne(b.w);
    return r;
}

__global__ __launch_bounds__(NTHR, 1)
void gru_mfma(const float* __restrict__ x,
              const float* __restrict__ Wih,
              const float* __restrict__ Whh,
              const float* __restrict__ bih,
              const float* __restrict__ bhh,
              unsigned int* __restrict__ hslab,   // [2][128][256] u32 (bf16 pairs)
              unsigned int* __restrict__ flags)   // [1024][4][64]
{
    extern __shared__ char smem[];
    float* CXf = (float*)(smem + OFF_CX);
    float* CHf = (float*)(smem + OFF_CH);

    const int tid  = threadIdx.x;
    const int lane = tid & 63;
    const int g    = blockIdx.x >> 6;          // batch group
    const int cg   = blockIdx.x & 63;          // column group
    const int rb0  = g * ROWS;
    const int hc0  = cg * HC;

    // ---- one-time: gather weight B-fragments (bf16) into LDS ----
    // B-frag for (kt,nt): lane l holds W[jcol(nt,l&15)][kt*32 + (l>>4)*8 .. +8]
#pragma unroll
    for (int i = 0; i < 4; ++i) {              // Wih: 16 slabs * 64 lanes
        int fw = tid + NTHR * i;
        int slab = fw >> 6, l = fw & 63;
        int kt = slab >> 1, nt = slab & 1;
        int c32 = nt * 16 + (l & 15);
        int wrow = (c32 < 24) ? ((c32 >> 3) * H_ + hc0 + (c32 & 7)) : 0;
        int kb = kt * 32 + ((l >> 4) << 3);
        *(short8*)(smem + OFF_BIH + fw * 16) = cvt8(Wih + wrow * I_ + kb);
    }
#pragma unroll
    for (int i = 0; i < 8; ++i) {              // Whh: 32 slabs * 64 lanes
        int fw = tid + NTHR * i;
        int slab = fw >> 6, l = fw & 63;
        int kt = slab >> 1, nt = slab & 1;
        int c32 = nt * 16 + (l & 15);
        int wrow = (c32 < 24) ? ((c32 >> 3) * H_ + hc0 + (c32 & 7)) : 0;
        int kb = kt * 32 + ((l >> 4) << 3);
        *(short8*)(smem + OFF_BHH + fw * 16) = cvt8(Whh + wrow * H_ + kb);
    }

    // finalize-thread constants
    const int frow = tid >> 3;                 // 0..31 local batch row
    const int fhl  = tid & 7;                  // 0..7 local col
    const int j    = hc0 + fhl;
    const float bR  = bih[j] + bhh[j];
    const float bZ  = bih[H_ + j] + bhh[H_ + j];
    const float bNx = bih[2 * H_ + j];
    const float bNh = bhh[2 * H_ + j];
    float hprev = 0.f;

    const int wv = tid >> 6;                   // wave id
    const int mt = wv & 1;                     // M-tile (16 rows)
    const int hh = wv >> 1;                    // K-half

    __syncthreads();

#pragma unroll 1
    for (int t = 0; t < T_; ++t) {
        // ---- stage x A-frags (cached loads + cvt) ----
#pragma unroll
        for (int i = 0; i < 4; ++i) {
            int fx = tid + NTHR * i;
            int slab = fx >> 6, l = fx & 63;
            int smt = slab & 1, skt = slab >> 1;
            int row = rb0 + smt * 16 + (l & 15);
            int kb = skt * 32 + ((l >> 4) << 3);
            *(short8*)(smem + OFF_AX + fx * 16) = cvt8(x + (row * T_ + t) * I_ + kb);
        }
        // ---- stage h A-frags (MALL-coherent bf16-pair loads, no cvt) ----
        const unsigned int* hsrc = hslab + (t & 1) * HSLAB;
#pragma unroll
        for (int i = 0; i < 8; ++i) {
            int fh = tid + NTHR * i;
            int slab = fh >> 6, l = fh & 63;
            int smt = slab & 1, skt = slab >> 1;
            int row = rb0 + smt * 16 + (l & 15);
            int kb2 = skt * 16 + ((l >> 4) << 2);        // u32 index (k/2)
            const unsigned int* s = hsrc + row * (H_/2) + kb2;
            unsigned int v0 = __hip_atomic_load(s + 0, __ATOMIC_RELAXED, __HIP_MEMORY_SCOPE_AGENT);
            unsigned int v1 = __hip_atomic_load(s + 1, __ATOMIC_RELAXED, __HIP_MEMORY_SCOPE_AGENT);
            unsigned int v2 = __hip_atomic_load(s + 2, __ATOMIC_RELAXED, __HIP_MEMORY_SCOPE_AGENT);
            unsigned int* dst = (unsigned int*)(smem + OFF_AH + fh * 16);
            unsigned int v3 = __hip_atomic_load(s + 3, __ATOMIC_RELAXED, __HIP_MEMORY_SCOPE_AGENT);
            uint4 vv = make_uint4(v0, v1, v2, v3);
            *(uint4*)dst = vv;
        }
        __syncthreads();

        // ---- MFMA: wave (mt,hh) computes its K-half partials ----
        f32x4 ax0 = {0.f,0.f,0.f,0.f}, ax1 = ax0, ah0 = ax0, ah1 = ax0;
#pragma unroll
        for (int kk = 0; kk < 4; ++kk) {       // x k-tiles
            int kt = hh * 4 + kk;
            short8 a  = *(const short8*)(smem + OFF_AX + ((kt*2 + mt)*64 + lane)*16);
            short8 b0 = *(const short8*)(smem + OFF_BIH + ((kt*2 + 0)*64 + lane)*16);
            short8 b1 = *(const short8*)(smem + OFF_BIH + ((kt*2 + 1)*64 + lane)*16);
            ax0 = __builtin_amdgcn_mfma_f32_16x16x32_bf16(a, b0, ax0, 0, 0, 0);
            ax1 = __builtin_amdgcn_mfma_f32_16x16x32_bf16(a, b1, ax1, 0, 0, 0);
        }
#pragma unroll
        for (int kk = 0; kk < 8; ++kk) {       // h k-tiles
            int kt = hh * 8 + kk;
            short8 a  = *(const short8*)(smem + OFF_AH + ((kt*2 + mt)*64 + lane)*16);
            short8 b0 = *(const short8*)(smem + OFF_BHH + ((kt*2 + 0)*64 + lane)*16);
            short8 b1 = *(const short8*)(smem + OFF_BHH + ((kt*2 + 1)*64 + lane)*16);
            ah0 = __builtin_amdgcn_mfma_f32_16x16x32_bf16(a, b0, ah0, 0, 0, 0);
            ah1 = __builtin_amdgcn_mfma_f32_16x16x32_bf16(a, b1, ah1, 0, 0, 0);
        }
        // dump partials: C row = (lane>>4)*4+reg (4 consecutive), col = lane&15 (+16 for nt=1)
        {
            int rbase = mt * 16 + ((lane >> 4) << 2);
            int c = lane & 15;
            *(f32x4*)(CXf + (hh*32 + c     )*36 + rbase) = ax0;
            *(f32x4*)(CXf + (hh*32 + 16 + c)*36 + rbase) = ax1;
            *(f32x4*)(CHf + (hh*32 + c     )*36 + rbase) = ah0;
            *(f32x4*)(CHf + (hh*32 + 16 + c)*36 + rbase) = ah1;
        }
        __syncthreads();

        // ---- finalize: one output (row,col) per thread; h-carry stays fp32 in reg ----
        {
            float sr  = CXf[(0*32 + fhl     )*36 + frow] + CXf[(1*32 + fhl     )*36 + frow]
                      + CHf[(0*32 + fhl     )*36 + frow] + CHf[(1*32 + fhl     )*36 + frow] + bR;
            float sz  = CXf[(0*32 + 8 + fhl )*36 + frow] + CXf[(1*32 + 8 + fhl )*36 + frow]
                      + CHf[(0*32 + 8 + fhl )*36 + frow] + CHf[(1*32 + 8 + fhl )*36 + frow] + bZ;
            float sxn = CXf[(0*32 + 16 + fhl)*36 + frow] + CXf[(1*32 + 16 + fhl)*36 + frow] + bNx;
            float shn = CHf[(0*32 + 16 + fhl)*36 + frow] + CHf[(1*32 + 16 + fhl)*36 + frow] + bNh;
            float r = 1.f / (1.f + __expf(-sr));
            float z = 1.f / (1.f + __expf(-sz));
            float n = tanhf(sxn + r * shn);
            float hnew = (1.f - z) * n + z * hprev;
            hprev = hnew;
            unsigned int hb = bf16rne(hnew);
            unsigned int ob = (unsigned int)__shfl_xor((int)hb, 1);
            if (!(tid & 1)) {
                unsigned int pk = (hb & 0xffffu) | (ob << 16);
                __hip_atomic_store(hslab + ((t + 1) & 1) * HSLAB + (rb0 + frow) * (H_/2) + ((hc0 + fhl) >> 1),
                                   pk, __ATOMIC_RELAXED, __HIP_MEMORY_SCOPE_AGENT);
            }
        }

        // ---- group barrier: flag store + wave-0 poll (all MALL-direct, no fences) ----
        __syncthreads();   // drains each wave's vmem (stores at coherence point)
        unsigned int* fl = flags + (t * BGROUPS + g) * 64;
        if (tid == 0)
            __hip_atomic_store(fl + cg, 1u, __ATOMIC_RELAXED, __HIP_MEMORY_SCOPE_AGENT);
        asm volatile("" ::: "memory");
        if (tid < 64) {
            unsigned int v;
            do {
                v = __hip_atomic_load(fl + tid, __ATOMIC_RELAXED, __HIP_MEMORY_SCOPE_AGENT);
            } while (!__all((int)(v != 0)));
        }
        __syncthreads();
    }
}

__global__ __launch_bounds__(256)
void fc_kernel(const unsigned int* __restrict__ hp,   // hslab[0]: [128][256] u32 bf16-pairs
               const float* __restrict__ fcW,
               const float* __restrict__ fcb,
               float* __restrict__ out)
{
    int gid = blockIdx.x * 256 + threadIdx.x;
    int b = gid >> 7, o = gid & 127;
    const unsigned int* hr = hp + b * (H_/2);
    const float* wr = fcW + o * H_;
    float acc = 0.f;
#pragma unroll 8
    for (int i = 0; i < H_/2; i += 4) {
        uint4 v = *(const uint4*)(hr + i);
        float4 w0 = *(const float4*)(wr + 2*i);
        float4 w1 = *(const float4*)(wr + 2*i + 4);
        acc += __builtin_bit_cast(float, v.x << 16)          * w0.x
             + __builtin_bit_cast(float, v.x & 0xffff0000u)  * w0.y
             + __builtin_bit_cast(float, v.y << 16)          * w0.z
             + __builtin_bit_cast(float, v.y & 0xffff0000u)  * w0.w
             + __builtin_bit_cast(float, v.z << 16)          * w1.x
             + __builtin_bit_cast(float, v.z & 0xffff0000u)  * w1.y
             + __builtin_bit_cast(float, v.w << 16)          * w1.z
             + __builtin_bit_cast(float, v.w & 0xffff0000u)  * w1.w;
    }
    out[gid] = acc + fcb[o];
}

extern "C" void kernel_launch(void* const* d_in, const int* in_sizes, int n_in,
                              void* d_out, int out_size, void* d_ws, size_t ws_size,
                              hipStream_t stream)
{
    const float* x   = (const float*)d_in[0];
    const float* Wih = (const float*)d_in[1];
    const float* Whh = (const float*)d_in[2];
    const float* bih = (const float*)d_in[3];
    const float* bhh = (const float*)d_in[4];
    const float* fcW = (const float*)d_in[5];
    const float* fcb = (const float*)d_in[6];
    float* out = (float*)d_out;

    unsigned int* hslab = (unsigned int*)d_ws;            // [2][128][256]
    unsigned int* flags = hslab + FLAGS_OFF;              // [1024][4][64]

    hipMemsetAsync(d_ws, 0, WS_INIT_BYTES, stream);       // h0 = 0, flags = 0 (every replay)

    hipFuncSetAttribute(reinterpret_cast<const void*>(gru_mfma),
                        hipFuncAttributeMaxDynamicSharedMemorySize, LDS_BYTES);

    hipLaunchKernelGGL(gru_mfma, dim3(NBLK), dim3(NTHR), LDS_BYTES, stream,
                       x, Wih, Whh, bih, bhh, hslab, flags);

    hipLaunchKernelGGL(fc_kernel, dim3((B_*O_)/256), dim3(256), 0, stream,
                       hslab, fcW, fcb, out);             // final h is slab 0
}

// Round 3
// 6596.295 us; speedup vs baseline: 7.9500x; 1.4946x over previous
//
#include <hip/hip_runtime.h>

#define B_ 128
#define T_ 1024
#define I_ 256
#define H_ 512
#define O_ 128

#define BGROUPS 4
#define ROWS 32                   // rows per block
#define CGROUPS 32
#define HC 16                     // h-cols per block
#define NBLK (BGROUPS*CGROUPS)    // 128
#define NTHR 512                  // 8 waves: (mt 0..1) x (kq 0..3)

// LDS layout (bytes)
#define OFF_AX 0                  // x A-frags: 8kt*2mt*64lane*16B = 16384
#define OFF_AH 16384              // h A-frags: 16kt*2mt*64*16 = 32768
#define OFF_CX 49152              // 4kq * 48n * 36row * 4B = 27648
#define OFF_CH 76800              // 27648
#define LDS_BYTES 104448

#define HSLAB (B_*(H_/2))         // u32 per h slab: 32768
#define FLAGS_OFF (2*HSLAB)
#define WS_INIT_BYTES ((2*HSLAB + T_*BGROUPS*CGROUPS)*4)   // 786432

typedef __attribute__((ext_vector_type(8))) short short8;
typedef __attribute__((ext_vector_type(4))) float f32x4;

__device__ __forceinline__ unsigned int bf16rne(float f) {
    unsigned int u = __builtin_bit_cast(unsigned int, f);
    u += 0x7fffu + ((u >> 16) & 1u);
    return u >> 16;
}
__device__ __forceinline__ short8 pack8(float4 a, float4 b) {
    short8 r;
    r[0]=(short)bf16rne(a.x); r[1]=(short)bf16rne(a.y); r[2]=(short)bf16rne(a.z); r[3]=(short)bf16rne(a.w);
    r[4]=(short)bf16rne(b.x); r[5]=(short)bf16rne(b.y); r[6]=(short)bf16rne(b.z); r[7]=(short)bf16rne(b.w);
    return r;
}
__device__ __forceinline__ short8 cvt8(const float* p) {
    return pack8(*(const float4*)p, *(const float4*)(p + 4));
}

__global__ __launch_bounds__(NTHR, 1)
void gru_mfma(const float* __restrict__ x,
              const float* __restrict__ Wih,
              const float* __restrict__ Whh,
              const float* __restrict__ bih,
              const float* __restrict__ bhh,
              unsigned int* __restrict__ hslab,   // [2][128][256] u32 (bf16 pairs)
              unsigned int* __restrict__ flags)   // [1024][4][32]
{
    extern __shared__ char smem[];
    float* CXf = (float*)(smem + OFF_CX);
    float* CHf = (float*)(smem + OFF_CH);

    const int tid  = threadIdx.x;
    const int lane = tid & 63;
    const int g    = blockIdx.x >> 5;          // batch group 0..3
    const int cg   = blockIdx.x & 31;          // column group 0..31
    const int rb0  = g * ROWS;
    const int hc0  = cg * HC;

    const int wv = tid >> 6;                   // 0..7
    const int mt = wv & 1;                     // M-tile (16 rows)
    const int kq = wv >> 1;                    // K-quarter

    // ---- one-time: weight B-fragments into REGISTERS (wave-resident) ----
    // B-frag(kt,nt): lane l holds W[nt*H + hc0 + (l&15)][kt*32 + (l>>4)*8 .. +8]
    short8 BX[2][3], BH[4][3];
#pragma unroll
    for (int xk = 0; xk < 2; ++xk) {
        int kt = kq * 2 + xk;
        int kb = kt * 32 + ((lane >> 4) << 3);
#pragma unroll
        for (int nt = 0; nt < 3; ++nt)
            BX[xk][nt] = cvt8(Wih + (nt * H_ + hc0 + (lane & 15)) * I_ + kb);
    }
#pragma unroll
    for (int hk = 0; hk < 4; ++hk) {
        int kt = kq * 4 + hk;
        int kb = kt * 32 + ((lane >> 4) << 3);
#pragma unroll
        for (int nt = 0; nt < 3; ++nt)
            BH[hk][nt] = cvt8(Whh + (nt * H_ + hc0 + (lane & 15)) * H_ + kb);
    }

    // finalize-thread constants (1 output per thread)
    const int frow = tid >> 4;                 // 0..31
    const int fcl  = tid & 15;                 // 0..15
    const int j    = hc0 + fcl;
    const float bR  = bih[j] + bhh[j];
    const float bZ  = bih[H_ + j] + bhh[H_ + j];
    const float bNx = bih[2 * H_ + j];
    const float bNh = bhh[2 * H_ + j];

    // x prefetch slots: fx0 = tid, fx1 = tid + 512 (16 slabs * 64 lanes)
    const int s0 = tid >> 6;                   // slab of fx0 = wv (0..7)
    const int s1 = 8 + s0;                     // slab of fx1
    const int kt0 = s0 >> 1, mt0 = s0 & 1;
    const int kt1 = s1 >> 1, mt1 = s1 & 1;
    const float* xp0 = x + ((rb0 + mt0 * 16 + (lane & 15)) * T_) * I_ + kt0 * 32 + ((lane >> 4) << 3);
    const float* xp1 = x + ((rb0 + mt1 * 16 + (lane & 15)) * T_) * I_ + kt1 * 32 + ((lane >> 4) << 3);

    // h staging slots: 4 per thread
    const unsigned int* hq[4];   // recomputed per step (slab base changes); store k-offsets
    int hoff[4];
#pragma unroll
    for (int i = 0; i < 4; ++i) {
        int fh = tid + NTHR * i;
        int slab = fh >> 6, l = fh & 63;
        int skt = slab >> 1, smt = slab & 1;
        hoff[i] = (rb0 + smt * 16 + (l & 15)) * (H_ / 2) + skt * 16 + ((l >> 4) << 2);
    }
    (void)hq;

    // prologue: prefetch x for t=0
    float4 x0a = *(const float4*)xp0, x0b = *(const float4*)(xp0 + 4);
    float4 x1a = *(const float4*)xp1, x1b = *(const float4*)(xp1 + 4);
    xp0 += I_; xp1 += I_;

#pragma unroll 1
    for (int t = 0; t < T_; ++t) {
        // ---- stage x A-frags from prefetch regs ----
        *(short8*)(smem + OFF_AX + tid * 16)              = pack8(x0a, x0b);
        *(short8*)(smem + OFF_AX + (tid + NTHR) * 16)     = pack8(x1a, x1b);

        // ---- stage h A-frags (MALL-coherent u32 loads) ----
        const unsigned int* hsrc = hslab + (t & 1) * HSLAB;
#pragma unroll
        for (int i = 0; i < 4; ++i) {
            const unsigned int* s = hsrc + hoff[i];
            unsigned int v0 = __hip_atomic_load(s + 0, __ATOMIC_RELAXED, __HIP_MEMORY_SCOPE_AGENT);
            unsigned int v1 = __hip_atomic_load(s + 1, __ATOMIC_RELAXED, __HIP_MEMORY_SCOPE_AGENT);
            unsigned int v2 = __hip_atomic_load(s + 2, __ATOMIC_RELAXED, __HIP_MEMORY_SCOPE_AGENT);
            unsigned int v3 = __hip_atomic_load(s + 3, __ATOMIC_RELAXED, __HIP_MEMORY_SCOPE_AGENT);
            *(uint4*)(smem + OFF_AH + (tid + NTHR * i) * 16) = make_uint4(v0, v1, v2, v3);
        }
        __syncthreads();

        // ---- MFMA: wave (mt,kq); B from registers, A from LDS ----
        f32x4 accx0 = {0.f,0.f,0.f,0.f}, accx1 = accx0, accx2 = accx0;
        f32x4 acch0 = accx0, acch1 = accx0, acch2 = accx0;
#pragma unroll
        for (int xk = 0; xk < 2; ++xk) {
            int kt = kq * 2 + xk;
            short8 a = *(const short8*)(smem + OFF_AX + ((kt * 2 + mt) * 64 + lane) * 16);
            accx0 = __builtin_amdgcn_mfma_f32_16x16x32_bf16(a, BX[xk][0], accx0, 0, 0, 0);
            accx1 = __builtin_amdgcn_mfma_f32_16x16x32_bf16(a, BX[xk][1], accx1, 0, 0, 0);
            accx2 = __builtin_amdgcn_mfma_f32_16x16x32_bf16(a, BX[xk][2], accx2, 0, 0, 0);
        }
#pragma unroll
        for (int hk = 0; hk < 4; ++hk) {
            int kt = kq * 4 + hk;
            short8 a = *(const short8*)(smem + OFF_AH + ((kt * 2 + mt) * 64 + lane) * 16);
            acch0 = __builtin_amdgcn_mfma_f32_16x16x32_bf16(a, BH[hk][0], acch0, 0, 0, 0);
            acch1 = __builtin_amdgcn_mfma_f32_16x16x32_bf16(a, BH[hk][1], acch1, 0, 0, 0);
            acch2 = __builtin_amdgcn_mfma_f32_16x16x32_bf16(a, BH[hk][2], acch2, 0, 0, 0);
        }
        // dump partials: C row = (lane>>4)*4+reg, col = lane&15
        {
            int rbase = mt * 16 + ((lane >> 4) << 2);
            int c = lane & 15;
            *(f32x4*)(CXf + (kq * 48 +      c) * 36 + rbase) = accx0;
            *(f32x4*)(CXf + (kq * 48 + 16 + c) * 36 + rbase) = accx1;
            *(f32x4*)(CXf + (kq * 48 + 32 + c) * 36 + rbase) = accx2;
            *(f32x4*)(CHf + (kq * 48 +      c) * 36 + rbase) = acch0;
            *(f32x4*)(CHf + (kq * 48 + 16 + c) * 36 + rbase) = acch1;
            *(f32x4*)(CHf + (kq * 48 + 32 + c) * 36 + rbase) = acch2;
        }
        __syncthreads();

        // ---- finalize: 1 output per thread; carry in MALL slab (bf16) ----
        {
            float sr = bR, sz = bZ, sxn = bNx, shn = bNh;
#pragma unroll
            for (int q = 0; q < 4; ++q) {
                sr  += CXf[(q * 48 +      fcl) * 36 + frow] + CHf[(q * 48 +      fcl) * 36 + frow];
                sz  += CXf[(q * 48 + 16 + fcl) * 36 + frow] + CHf[(q * 48 + 16 + fcl) * 36 + frow];
                sxn += CXf[(q * 48 + 32 + fcl) * 36 + frow];
                shn += CHf[(q * 48 + 32 + fcl) * 36 + frow];
            }
            // hprev from the staged LDS tile (bf16 value — matches what peers used)
            unsigned int hpu = *(unsigned short*)(smem + OFF_AH +
                ((((j >> 5) & 15) * 2 + (frow >> 4)) * 64 + ((frow & 15) | (((j >> 3) & 3) << 4))) * 16
                + ((j & 7) << 1));
            float hprev = __builtin_bit_cast(float, hpu << 16);
            float r = 1.f / (1.f + __expf(-sr));
            float z = 1.f / (1.f + __expf(-sz));
            float n = tanhf(sxn + r * shn);
            float hnew = (1.f - z) * n + z * hprev;
            unsigned int hb = bf16rne(hnew);
            unsigned int ob = (unsigned int)__shfl_xor((int)hb, 1);
            if (!(tid & 1)) {
                unsigned int pk = (hb & 0xffffu) | (ob << 16);
                __hip_atomic_store(hslab + ((t + 1) & 1) * HSLAB + (rb0 + frow) * (H_ / 2) + (j >> 1),
                                   pk, __ATOMIC_RELAXED, __HIP_MEMORY_SCOPE_AGENT);
            }
        }

        // ---- barrier: drain stores, flag, prefetch x(t+1) under the poll ----
        __syncthreads();                       // compiler emits vmcnt(0) drain before s_barrier
        unsigned int* fl = flags + (t * BGROUPS + g) * CGROUPS;
        if (tid == 0)
            __hip_atomic_store(fl + cg, 1u, __ATOMIC_RELAXED, __HIP_MEMORY_SCOPE_AGENT);
        if (t + 1 < T_) {                      // overlap HBM latency with the poll
            x0a = *(const float4*)xp0; x0b = *(const float4*)(xp0 + 4);
            x1a = *(const float4*)xp1; x1b = *(const float4*)(xp1 + 4);
            xp0 += I_; xp1 += I_;
        }
        if (tid < 64) {
            unsigned int v;
            do {
                v = __hip_atomic_load(fl + (lane & 31), __ATOMIC_RELAXED, __HIP_MEMORY_SCOPE_AGENT);
            } while (!__all((int)(v != 0)));
        }
        __syncthreads();
    }
}

__global__ __launch_bounds__(256)
void fc_kernel(const unsigned int* __restrict__ hp,   // hslab[0]: [128][256] u32 bf16-pairs
               const float* __restrict__ fcW,
               const float* __restrict__ fcb,
               float* __restrict__ out)
{
    int gid = blockIdx.x * 256 + threadIdx.x;
    int b = gid >> 7, o = gid & 127;
    const unsigned int* hr = hp + b * (H_ / 2);
    const float* wr = fcW + o * H_;
    float acc = 0.f;
#pragma unroll 8
    for (int i = 0; i < H_ / 2; i += 4) {
        uint4 v = *(const uint4*)(hr + i);
        float4 w0 = *(const float4*)(wr + 2 * i);
        float4 w1 = *(const float4*)(wr + 2 * i + 4);
        acc += __builtin_bit_cast(float, v.x << 16)          * w0.x
             + __builtin_bit_cast(float, v.x & 0xffff0000u)  * w0.y
             + __builtin_bit_cast(float, v.y << 16)          * w0.z
             + __builtin_bit_cast(float, v.y & 0xffff0000u)  * w0.w
             + __builtin_bit_cast(float, v.z << 16)          * w1.x
             + __builtin_bit_cast(float, v.z & 0xffff0000u)  * w1.y
             + __builtin_bit_cast(float, v.w << 16)          * w1.z
             + __builtin_bit_cast(float, v.w & 0xffff0000u)  * w1.w;
    }
    out[gid] = acc + fcb[o];
}

extern "C" void kernel_launch(void* const* d_in, const int* in_sizes, int n_in,
                              void* d_out, int out_size, void* d_ws, size_t ws_size,
                              hipStream_t stream)
{
    const float* x   = (const float*)d_in[0];
    const float* Wih = (const float*)d_in[1];
    const float* Whh = (const float*)d_in[2];
    const float* bih = (const float*)d_in[3];
    const float* bhh = (const float*)d_in[4];
    const float* fcW = (const float*)d_in[5];
    const float* fcb = (const float*)d_in[6];
    float* out = (float*)d_out;

    unsigned int* hslab = (unsigned int*)d_ws;            // [2][128][256]
    unsigned int* flags = hslab + FLAGS_OFF;              // [1024][4][32]

    hipMemsetAsync(d_ws, 0, WS_INIT_BYTES, stream);       // h0 = 0, flags = 0 (every replay)

    hipFuncSetAttribute(reinterpret_cast<const void*>(gru_mfma),
                        hipFuncAttributeMaxDynamicSharedMemorySize, LDS_BYTES);

    hipLaunchKernelGGL(gru_mfma, dim3(NBLK), dim3(NTHR), LDS_BYTES, stream,
                       x, Wih, Whh, bih, bhh, hslab, flags);

    hipLaunchKernelGGL(fc_kernel, dim3((B_ * O_) / 256), dim3(256), 0, stream,
                       hslab, fcW, fcb, out);             // final h is slab 0
}

// Round 4
// 4016.197 us; speedup vs baseline: 13.0572x; 1.6424x over previous
//
#include <hip/hip_runtime.h>

#define B_ 128
#define T_ 1024
#define I_ 256
#define H_ 512
#define O_ 128

#define BGROUPS 4
#define ROWS 32                   // batch rows per block
#define CGROUPS 32
#define HC 16                     // h-cols per block
#define NBLK (BGROUPS*CGROUPS)    // 128
#define NTHR 512                  // 8 waves: (mt 0..1) x (kq 0..3)

#define HSLAB (B_*(H_/2))         // u32 per h slab: 32768
#define FLAGS_OFF (2*HSLAB)
#define WS_INIT_BYTES ((2*HSLAB + T_*BGROUPS*CGROUPS)*4)   // 786432

#define LDS_BYTES 32768           // 4 C-slabs x 8KB, linear frag layout

typedef __attribute__((ext_vector_type(8))) short short8;
typedef __attribute__((ext_vector_type(4))) float f32x4;

__device__ __forceinline__ unsigned int bf16rne(float f) {
    unsigned int u = __builtin_bit_cast(unsigned int, f);
    u += 0x7fffu + ((u >> 16) & 1u);
    return u >> 16;
}
__device__ __forceinline__ short8 pack8(float4 a, float4 b) {
    short8 r;
    r[0]=(short)bf16rne(a.x); r[1]=(short)bf16rne(a.y); r[2]=(short)bf16rne(a.z); r[3]=(short)bf16rne(a.w);
    r[4]=(short)bf16rne(b.x); r[5]=(short)bf16rne(b.y); r[6]=(short)bf16rne(b.z); r[7]=(short)bf16rne(b.w);
    return r;
}
__device__ __forceinline__ short8 cvt8(const float* p) {
    return pack8(*(const float4*)p, *(const float4*)(p + 4));
}

__global__ __launch_bounds__(NTHR, 1)
void gru_mfma(const float* __restrict__ x,
              const float* __restrict__ Wih,
              const float* __restrict__ Whh,
              const float* __restrict__ bih,
              const float* __restrict__ bhh,
              unsigned int* __restrict__ hslab,   // [2][128][256] u32 (bf16 pairs)
              unsigned int* __restrict__ flags)   // [1024][4][32]
{
    __shared__ __align__(16) char smem[LDS_BYTES];

    const int tid  = threadIdx.x;
    const int lane = tid & 63;
    const int g    = blockIdx.x >> 5;          // batch group 0..3
    const int cg   = blockIdx.x & 31;          // column group 0..31
    const int rb0  = g * ROWS;
    const int hc0  = cg * HC;

    const int wv = tid >> 6;                   // 0..7
    const int mt = wv & 1;                     // M-tile (16 rows)
    const int kq = wv >> 1;                    // K-quarter

    // ---- one-time: weight B-fragments into registers ----
    // B-frag(kt,nt): lane l holds W[nt*H + hc0 + (l&15)][kt*32 + (l>>4)*8 .. +8]
    short8 BX[2][3], BH[4][3];
#pragma unroll
    for (int xk = 0; xk < 2; ++xk) {
        int kb = (kq * 2 + xk) * 32 + ((lane >> 4) << 3);
#pragma unroll
        for (int nt = 0; nt < 3; ++nt)
            BX[xk][nt] = cvt8(Wih + (nt * H_ + hc0 + (lane & 15)) * I_ + kb);
    }
#pragma unroll
    for (int hk = 0; hk < 4; ++hk) {
        int kb = (kq * 4 + hk) * 32 + ((lane >> 4) << 3);
#pragma unroll
        for (int nt = 0; nt < 3; ++nt)
            BH[hk][nt] = cvt8(Whh + (nt * H_ + hc0 + (lane & 15)) * H_ + kb);
    }

    // A-frag geometry for this lane
    const int arow = rb0 + mt * 16 + (lane & 15);
    const int kch  = lane >> 4;                // k-chunk 0..3

    // finalize constants: thread owns output (frow, fcl)
    const int frow = tid >> 4;                 // 0..31
    const int fcl  = tid & 15;                 // 0..15
    const int j    = hc0 + fcl;
    const float bR  = bih[j] + bhh[j];
    const float bZ  = bih[H_ + j] + bhh[H_ + j];
    const float bNx = bih[2 * H_ + j];
    const float bNh = bhh[2 * H_ + j];
    const int mtf  = frow >> 4;
    const int r16  = frow & 15;
    const int fbase = ((((r16 >> 2) << 4) | fcl) << 2) + (r16 & 3);   // lane'*4 + reg
    float hprev = 0.f;

    // x prefetch pointers (this wave's own 2 k-slices, 8 floats each)
    const float* xp0 = x + (arow * T_) * I_ + (kq * 2) * 32 + kch * 8;
    const float* xp1 = xp0 + 32;
    float4 pxa0 = *(const float4*)xp0, pxa1 = *(const float4*)(xp0 + 4);
    float4 pxb0 = *(const float4*)xp1, pxb1 = *(const float4*)(xp1 + 4);
    xp0 += I_; xp1 += I_;

#pragma unroll 1
    for (int t = 0; t < T_; ++t) {
        // ---- wait for h_t (flags set by all group blocks at end of t-1) ----
        if (t > 0) {
            const unsigned int* fl = flags + ((t - 1) * BGROUPS + g) * CGROUPS;
            if (tid < 64) {
                unsigned int v;
                do {
                    v = __hip_atomic_load(fl + (lane & 31), __ATOMIC_RELAXED, __HIP_MEMORY_SCOPE_AGENT);
                } while (!__all((int)(v != 0)));
            }
        }
        __syncthreads();

        // ---- issue all h A-frag loads (MALL-coherent, batched) ----
        const unsigned int* hrowp = hslab + (t & 1) * HSLAB + arow * (H_ / 2) + kch * 4;
        unsigned long long hq[8];
#pragma unroll
        for (int hk = 0; hk < 4; ++hk) {
            const unsigned long long* p =
                (const unsigned long long*)(hrowp + (kq * 4 + hk) * 16);
            hq[2 * hk]     = __hip_atomic_load(p,     __ATOMIC_RELAXED, __HIP_MEMORY_SCOPE_AGENT);
            hq[2 * hk + 1] = __hip_atomic_load(p + 1, __ATOMIC_RELAXED, __HIP_MEMORY_SCOPE_AGENT);
        }

        // ---- x part while h loads fly ----
        f32x4 accR = {0.f, 0.f, 0.f, 0.f}, accZ = accR, accNX = accR, accNH = accR;
        {
            short8 ax0 = pack8(pxa0, pxa1);
            short8 ax1 = pack8(pxb0, pxb1);
            accR  = __builtin_amdgcn_mfma_f32_16x16x32_bf16(ax0, BX[0][0], accR, 0, 0, 0);
            accZ  = __builtin_amdgcn_mfma_f32_16x16x32_bf16(ax0, BX[0][1], accZ, 0, 0, 0);
            accNX = __builtin_amdgcn_mfma_f32_16x16x32_bf16(ax0, BX[0][2], accNX, 0, 0, 0);
            accR  = __builtin_amdgcn_mfma_f32_16x16x32_bf16(ax1, BX[1][0], accR, 0, 0, 0);
            accZ  = __builtin_amdgcn_mfma_f32_16x16x32_bf16(ax1, BX[1][1], accZ, 0, 0, 0);
            accNX = __builtin_amdgcn_mfma_f32_16x16x32_bf16(ax1, BX[1][2], accNX, 0, 0, 0);
        }
        // ---- h part (r/z accumulate into same accs; n kept split) ----
#pragma unroll
        for (int hk = 0; hk < 4; ++hk) {
            union { unsigned long long q[2]; short8 s; } u;
            u.q[0] = hq[2 * hk]; u.q[1] = hq[2 * hk + 1];
            accR  = __builtin_amdgcn_mfma_f32_16x16x32_bf16(u.s, BH[hk][0], accR, 0, 0, 0);
            accZ  = __builtin_amdgcn_mfma_f32_16x16x32_bf16(u.s, BH[hk][1], accZ, 0, 0, 0);
            accNH = __builtin_amdgcn_mfma_f32_16x16x32_bf16(u.s, BH[hk][2], accNH, 0, 0, 0);
        }

        // ---- dump partials: linear frag layout, zero bank conflicts ----
        {
            char* cb = smem + wv * 1024 + lane * 16;
            *(f32x4*)(cb +     0) = accR;
            *(f32x4*)(cb +  8192) = accZ;
            *(f32x4*)(cb + 16384) = accNX;
            *(f32x4*)(cb + 24576) = accNH;
        }
        __syncthreads();

        // ---- finalize: sum 4 K-quarters, gates, store bf16 pair ----
        {
            const float* CB = (const float*)smem;
            float sr = bR, sz = bZ, sxn = bNx, shn = bNh;
#pragma unroll
            for (int q = 0; q < 4; ++q) {
                int base = (q * 2 + mtf) * 256 + fbase;
                sr  += CB[base];
                sz  += CB[2048 + base];
                sxn += CB[4096 + base];
                shn += CB[6144 + base];
            }
            float r = 1.f / (1.f + __expf(-sr));
            float z = 1.f / (1.f + __expf(-sz));
            float e2 = __expf(2.f * (sxn + r * shn));
            float n = 1.f - 2.f / (e2 + 1.f);          // tanh, overflow-safe
            float hnew = (1.f - z) * n + z * hprev;
            hprev = hnew;
            unsigned int hb = bf16rne(hnew);
            unsigned int ob = (unsigned int)__shfl_xor((int)hb, 1);
            if (!(fcl & 1)) {
                unsigned int pk = (hb & 0xffffu) | (ob << 16);
                __hip_atomic_store(hslab + ((t + 1) & 1) * HSLAB + (rb0 + frow) * (H_ / 2) + (j >> 1),
                                   pk, __ATOMIC_RELAXED, __HIP_MEMORY_SCOPE_AGENT);
            }
        }
        __syncthreads();                       // vmcnt(0) drain: all stores at MALL

        // ---- signal + prefetch x(t+1) under the next poll window ----
        if (tid == 0)
            __hip_atomic_store(flags + (t * BGROUPS + g) * CGROUPS + cg, 1u,
                               __ATOMIC_RELAXED, __HIP_MEMORY_SCOPE_AGENT);
        if (t + 1 < T_) {
            pxa0 = *(const float4*)xp0; pxa1 = *(const float4*)(xp0 + 4);
            pxb0 = *(const float4*)xp1; pxb1 = *(const float4*)(xp1 + 4);
            xp0 += I_; xp1 += I_;
        }
    }
}

__global__ __launch_bounds__(256)
void fc_kernel(const unsigned int* __restrict__ hp,   // hslab[0]: [128][256] u32 bf16-pairs
               const float* __restrict__ fcW,
               const float* __restrict__ fcb,
               float* __restrict__ out)
{
    int gid = blockIdx.x * 256 + threadIdx.x;
    int b = gid >> 7, o = gid & 127;
    const unsigned int* hr = hp + b * (H_ / 2);
    const float* wr = fcW + o * H_;
    float acc = 0.f;
#pragma unroll 8
    for (int i = 0; i < H_ / 2; i += 4) {
        uint4 v = *(const uint4*)(hr + i);
        float4 w0 = *(const float4*)(wr + 2 * i);
        float4 w1 = *(const float4*)(wr + 2 * i + 4);
        acc += __builtin_bit_cast(float, v.x << 16)          * w0.x
             + __builtin_bit_cast(float, v.x & 0xffff0000u)  * w0.y
             + __builtin_bit_cast(float, v.y << 16)          * w0.z
             + __builtin_bit_cast(float, v.y & 0xffff0000u)  * w0.w
             + __builtin_bit_cast(float, v.z << 16)          * w1.x
             + __builtin_bit_cast(float, v.z & 0xffff0000u)  * w1.y
             + __builtin_bit_cast(float, v.w << 16)          * w1.z
             + __builtin_bit_cast(float, v.w & 0xffff0000u)  * w1.w;
    }
    out[gid] = acc + fcb[o];
}

extern "C" void kernel_launch(void* const* d_in, const int* in_sizes, int n_in,
                              void* d_out, int out_size, void* d_ws, size_t ws_size,
                              hipStream_t stream)
{
    const float* x   = (const float*)d_in[0];
    const float* Wih = (const float*)d_in[1];
    const float* Whh = (const float*)d_in[2];
    const float* bih = (const float*)d_in[3];
    const float* bhh = (const float*)d_in[4];
    const float* fcW = (const float*)d_in[5];
    const float* fcb = (const float*)d_in[6];
    float* out = (float*)d_out;

    unsigned int* hslab = (unsigned int*)d_ws;            // [2][128][256]
    unsigned int* flags = hslab + FLAGS_OFF;              // [1024][4][32]

    hipMemsetAsync(d_ws, 0, WS_INIT_BYTES, stream);       // h0 = 0, flags = 0 (every replay)

    hipLaunchKernelGGL(gru_mfma, dim3(NBLK), dim3(NTHR), 0, stream,
                       x, Wih, Whh, bih, bhh, hslab, flags);

    hipLaunchKernelGGL(fc_kernel, dim3((B_ * O_) / 256), dim3(256), 0, stream,
                       hslab, fcW, fcb, out);             // final h is slab 0 (T even)
}